// Round 5
// baseline (562.121 us; speedup 1.0000x reference)
//
#include <hip/hip_runtime.h>
#include <stdint.h>

// GhostAttention on MI355X (gfx950). B=2, T=2048, C=2048, H=16, hd=128.
// All-fp16 pipeline: convert -> fused QKV GEMM (BK=64, conflict-free LDS;
// V written transposed via LDS epilogue) -> causal relu-attention
// (linear normalizer, k-tile=128, 4 barriers/iter) -> out GEMM (fp32 out).

typedef unsigned short u16;
typedef _Float16 f16x8 __attribute__((ext_vector_type(8)));
typedef float floatx4 __attribute__((ext_vector_type(4)));
typedef unsigned short ushort8_t __attribute__((ext_vector_type(8)));

__device__ __forceinline__ u16 f2h(float f) {
  _Float16 h = (_Float16)f;                  // v_cvt_f16_f32, RNE
  return __builtin_bit_cast(u16, h);
}
__device__ __forceinline__ f16x8 ld_frag(const u16* p) {
  return __builtin_bit_cast(f16x8, *(const ushort8_t*)p);
}

// XOR-swizzled LDS offset: row length R elems (R%8==0), cprMask = R/8-1.
// Rows >=128B span all 32 banks -> uniform 2-way aliasing on b128 reads (free).
__device__ __forceinline__ int swz(int row, int col, int R, int cprMask) {
  int chunk = ((col >> 3) ^ row) & cprMask;
  return row * R + chunk * 8 + (col & 7);
}

__device__ __forceinline__ void async_copy16(const void* g, void* l) {
  __builtin_amdgcn_global_load_lds(
      (const __attribute__((address_space(1))) void*)g,
      (__attribute__((address_space(3))) void*)l, 16, 0, 0);
}

// Stage (NINST*2048/R) rows x R fp16 from global (row stride grs) into swizzled LDS.
template<int R, int NINST>
__device__ __forceinline__ void stage_swz(const u16* g, size_t grs, u16* lds, int tid) {
  constexpr int CPR = R / 8;
  #pragma unroll
  for (int i = 0; i < NINST; ++i) {
    int f = tid + i * 256;
    int row = f / CPR;
    int sc = f & (CPR - 1);
    int c = sc ^ (row & (CPR - 1));
    async_copy16(g + (size_t)row * grs + c * 8, (char*)lds + f * 16);
  }
}

// ---------------------------------------------------------------- converts
__global__ void f32_to_f16_kernel(const float* __restrict__ in, u16* __restrict__ out, int n) {
  int i = (blockIdx.x * blockDim.x + threadIdx.x) * 4;
  if (i < n) {
    float4 v = *(const float4*)(in + i);
    ushort4 o;
    o.x = f2h(v.x); o.y = f2h(v.y); o.z = f2h(v.z); o.w = f2h(v.w);
    *(ushort4*)(out + i) = o;
  }
}

__global__ void w4_to_f16_kernel(const float* w0, const float* w1, const float* w2, const float* w3,
                                 u16* o0, u16* o1, u16* o2, u16* o3, int n) {
  const float* in = (blockIdx.y == 0) ? w0 : (blockIdx.y == 1) ? w1 : (blockIdx.y == 2) ? w2 : w3;
  u16* out = (blockIdx.y == 0) ? o0 : (blockIdx.y == 1) ? o1 : (blockIdx.y == 2) ? o2 : o3;
  int i = (blockIdx.x * blockDim.x + threadIdx.x) * 4;
  if (i < n) {
    float4 v = *(const float4*)(in + i);
    ushort4 o;
    o.x = f2h(v.x); o.y = f2h(v.y); o.z = f2h(v.z); o.w = f2h(v.w);
    *(ushort4*)(out + i) = o;
  }
}

// ---------------------------------------------------------------- GEMM (B^T)
// C = A[M,K] @ B[N,K]^T, fp16 in, fp32 accum. 128x128 tile, BK=64.
// MODE 1: fp32 row-major C0[M,N]   (final projection)
// MODE 3: fused QKV: N=6144; sel = n/2048 -> Q (C0) / K (C1) head-major
//         [B,H,T,128]; V (C2) written TRANSPOSED [B,H,128,T] via LDS.
template<int MODE>
__global__ __launch_bounds__(256, 3) void gemm_bt(
    const u16* __restrict__ A,
    const u16* __restrict__ B0, const u16* __restrict__ B1, const u16* __restrict__ B2,
    void* __restrict__ C0, void* __restrict__ C1, void* __restrict__ C2,
    const int M, const int N, const int K)
{
  __shared__ __align__(16) u16 smem[128 * 128];  // 32 KB: As|Bs, reused by V-epilogue
  u16* As = smem;
  u16* Bs = smem + 128 * 64;
  const int tid = threadIdx.x;
  const int w = tid >> 6, lane = tid & 63, lr = lane & 15, lq = lane >> 4;
  const int bn0 = blockIdx.x * 128, bm0 = blockIdx.y * 128;
  const int wm = (w >> 1) * 64, wn = (w & 1) * 64;
  floatx4 acc[4][4] = {};
  const u16* Ab = A + (size_t)bm0 * K;
  const int sel = bn0 >> 11;                  // which output (MODE 3)
  const u16* Bb;
  if (MODE == 3) {
    const u16* Bsel = (sel == 0) ? B0 : (sel == 1) ? B1 : B2;
    Bb = Bsel + (size_t)(bn0 & 2047) * K;
  } else {
    Bb = B0 + (size_t)bn0 * K;
  }

  for (int k0 = 0; k0 < K; k0 += 64) {
    __syncthreads();
    stage_swz<64, 4>(Ab + k0, K, As, tid);
    stage_swz<64, 4>(Bb + k0, K, Bs, tid);
    __syncthreads();
    #pragma unroll
    for (int kk = 0; kk < 2; ++kk) {
      f16x8 af[4], bfr[4];
      #pragma unroll
      for (int t = 0; t < 4; ++t) {
        af[t]  = ld_frag(&As[swz(wm + t * 16 + lr, kk * 32 + lq * 8, 64, 7)]);
        bfr[t] = ld_frag(&Bs[swz(wn + t * 16 + lr, kk * 32 + lq * 8, 64, 7)]);
      }
      #pragma unroll
      for (int mt = 0; mt < 4; ++mt)
        #pragma unroll
        for (int nt = 0; nt < 4; ++nt)
          acc[mt][nt] = __builtin_amdgcn_mfma_f32_16x16x32_f16(af[mt], bfr[nt], acc[mt][nt], 0, 0, 0);
    }
  }

  // epilogue: C/D layout col=lane&15, row=(lane>>4)*4+reg
  if (MODE == 3 && sel == 2) {
    // V: transpose 128x128 tile through LDS, write Vt [BH,128,T] coalesced.
    __syncthreads();                          // all waves done reading As/Bs
    #pragma unroll
    for (int mt = 0; mt < 4; ++mt) {
      #pragma unroll
      for (int nt = 0; nt < 4; ++nt) {
        #pragma unroll
        for (int r = 0; r < 4; ++r) {
          const int tl = wm + mt * 16 + lq * 4 + r;   // local t
          const int d  = wn + nt * 16 + lr;           // local d
          smem[swz(d, tl, 128, 15)] = f2h(acc[mt][nt][r]);
        }
      }
    }
    __syncthreads();
    const int bb = bm0 >> 11, t0 = bm0 & 2047;
    const int h = (bn0 & 2047) >> 7;
    u16* base = (u16*)C2 + ((size_t)(bb * 16 + h) * 128) * 2048 + t0;
    #pragma unroll
    for (int i = 0; i < 8; ++i) {
      const int f = tid + i * 256;           // chunk id 0..2047
      const int row = f >> 4;                // local d
      const int cc = f & 15;                 // stored chunk
      const int c = cc ^ (row & 15);         // logical t-chunk
      ushort8_t v = *(const ushort8_t*)&smem[row * 128 + cc * 8];
      *(ushort8_t*)(base + (size_t)row * 2048 + c * 8) = v;
    }
  } else {
    #pragma unroll
    for (int mt = 0; mt < 4; ++mt) {
      #pragma unroll
      for (int nt = 0; nt < 4; ++nt) {
        #pragma unroll
        for (int r = 0; r < 4; ++r) {
          const int m = bm0 + wm + mt * 16 + lq * 4 + r;
          const int n = bn0 + wn + nt * 16 + lr;
          const float v = acc[mt][nt][r];
          if (MODE == 1) {
            ((float*)C0)[(size_t)m * N + n] = v;
          } else {
            const int nn = n & 2047;
            const int bb = m >> 11, t = m & 2047, h = nn >> 7, d = nn & 127;
            const size_t idx = (((size_t)(bb * 16 + h) * 2048) + t) * 128 + d;
            u16* Cs = (sel == 0) ? (u16*)C0 : (u16*)C1;
            Cs[idx] = f2h(v);
          }
        }
      }
    }
  }
}

// ---------------------------------------------------------------- attention
// Block: one (bh, 128-row q-tile). k-tiles of 128 (4 barriers/iter vs 6 for
// two 64-tiles). out = (P@V)/(P@1 + eps), P = relu(S*scale + 0.1), causal.
// Ps aliases Ks (dead after QK). LDS 64 KB, 2 blocks/CU.
__global__ __launch_bounds__(256, 2) void attn_kernel(
    const u16* __restrict__ Qh, const u16* __restrict__ Kh,
    const u16* __restrict__ Vt, u16* __restrict__ Ob)
{
  __shared__ __align__(16) u16 smem[32768];   // 64 KB
  u16* Ks  = smem;            // [128][128] swz cpr16; aliased by Ps
  u16* Ps  = smem;
  u16* Vts = smem + 16384;    // [128 d][128 k] swz cpr16
  const int tid = threadIdx.x;
  const int w = tid >> 6, lane = tid & 63, lr = lane & 15, lq = lane >> 4;
  const int bh = blockIdx.x;
  const int y = blockIdx.y;
  // complementary interleave: blocks y and y+8 have qt summing to 15 ->
  // uniform k-iter load across CUs
  const int qt = (y < 8) ? (15 - y) : (y - 8);
  const int q0 = qt * 128;
  const size_t bhT = (size_t)bh * 2048;

  // Q tile 128x128 -> LDS (Ks region) -> registers
  f16x8 qf[2][4];
  stage_swz<128, 8>(Qh + (bhT + q0) * 128, 128, smem, tid);
  __syncthreads();
  #pragma unroll
  for (int mt = 0; mt < 2; ++mt)
    #pragma unroll
    for (int kk = 0; kk < 4; ++kk)
      qf[mt][kk] = ld_frag(&smem[swz(w * 32 + mt * 16 + lr, kk * 32 + lq * 8, 128, 15)]);
  __syncthreads();

  floatx4 oacc[2][8] = {};
  floatx4 den[2] = {};
  const ushort8_t onesu = {0x3C00, 0x3C00, 0x3C00, 0x3C00, 0x3C00, 0x3C00, 0x3C00, 0x3C00};
  const f16x8 ones = __builtin_bit_cast(f16x8, onesu);
  const float scale = 0.08838834764831845f;   // 1/sqrt(128)

  for (int k0 = 0; k0 <= q0; k0 += 128) {
    stage_swz<128, 8>(Kh + (bhT + k0) * 128, 128, Ks, tid);
    stage_swz<128, 8>(Vt + (size_t)bh * 128 * 2048 + k0, 2048, Vts, tid);
    __syncthreads();                          // B1: staging visible

    // S = Q K^T : 32 q-rows x 128 keys per wave
    floatx4 s[2][8] = {};
    #pragma unroll
    for (int kk = 0; kk < 4; ++kk) {
      f16x8 kf[8];
      #pragma unroll
      for (int nt = 0; nt < 8; ++nt)
        kf[nt] = ld_frag(&Ks[swz(nt * 16 + lr, kk * 32 + lq * 8, 128, 15)]);
      #pragma unroll
      for (int mt = 0; mt < 2; ++mt)
        #pragma unroll
        for (int nt = 0; nt < 8; ++nt)
          s[mt][nt] = __builtin_amdgcn_mfma_f32_16x16x32_f16(qf[mt][kk], kf[nt], s[mt][nt], 0, 0, 0);
    }
    __syncthreads();                          // B2: all waves done reading Ks

    // P = relu(S*scale + 0.1); causal mask only on the diagonal tile (k0==q0)
    if (k0 < q0) {
      #pragma unroll
      for (int mt = 0; mt < 2; ++mt) {
        const int rb = w * 32 + mt * 16 + lq * 4;
        #pragma unroll
        for (int nt = 0; nt < 8; ++nt) {
          const int col = nt * 16 + lr;
          #pragma unroll
          for (int r = 0; r < 4; ++r)
            Ps[swz(rb + r, col, 128, 15)] = f2h(fmaxf(s[mt][nt][r] * scale + 0.1f, 0.0f));
        }
      }
    } else {
      #pragma unroll
      for (int mt = 0; mt < 2; ++mt) {
        const int rb = w * 32 + mt * 16 + lq * 4;
        #pragma unroll
        for (int nt = 0; nt < 8; ++nt) {
          const int col = nt * 16 + lr;
          const int kg = k0 + col;
          #pragma unroll
          for (int r = 0; r < 4; ++r) {
            float v = fmaxf(s[mt][nt][r] * scale + 0.1f, 0.0f);
            v = (kg <= q0 + rb + r) ? v : 0.0f;
            Ps[swz(rb + r, col, 128, 15)] = f2h(v);
          }
        }
      }
    }
    __syncthreads();                          // B3: Ps visible

    // O += P @ Vt^T ; den += P @ 1
    #pragma unroll
    for (int kk = 0; kk < 4; ++kk) {
      f16x8 pf[2];
      #pragma unroll
      for (int mt = 0; mt < 2; ++mt)
        pf[mt] = ld_frag(&Ps[swz(w * 32 + mt * 16 + lr, kk * 32 + lq * 8, 128, 15)]);
      #pragma unroll
      for (int mt = 0; mt < 2; ++mt)
        den[mt] = __builtin_amdgcn_mfma_f32_16x16x32_f16(pf[mt], ones, den[mt], 0, 0, 0);
      #pragma unroll
      for (int dt = 0; dt < 8; ++dt) {
        f16x8 vf = ld_frag(&Vts[swz(dt * 16 + lr, kk * 32 + lq * 8, 128, 15)]);
        #pragma unroll
        for (int mt = 0; mt < 2; ++mt)
          oacc[mt][dt] = __builtin_amdgcn_mfma_f32_16x16x32_f16(pf[mt], vf, oacc[mt][dt], 0, 0, 0);
      }
    }
    __syncthreads();                          // B4: done with Ps/Vts
  }

  // epilogue: Ob [B*T, 2048] fp16 (row = b*2048 + t, col = h*128 + d)
  const int b = bh >> 4, h = bh & 15;
  #pragma unroll
  for (int mt = 0; mt < 2; ++mt) {
    #pragma unroll
    for (int r = 0; r < 4; ++r) {
      const int qrow = w * 32 + mt * 16 + lq * 4 + r;
      const float inv = 1.0f / (den[mt][r] + 1e-6f);
      u16* dst = Ob + ((size_t)(b * 2048 + q0 + qrow)) * 2048 + h * 128;
      #pragma unroll
      for (int dt = 0; dt < 8; ++dt)
        dst[dt * 16 + lr] = f2h(oacc[mt][dt][r] * inv);
    }
  }
}

// ---------------------------------------------------------------- launch
extern "C" void kernel_launch(void* const* d_in, const int* in_sizes, int n_in,
                              void* d_out, int out_size, void* d_ws, size_t ws_size,
                              hipStream_t stream) {
  const float* x  = (const float*)d_in[0];
  const float* Wq = (const float*)d_in[1];
  const float* Wk = (const float*)d_in[2];
  const float* Wv = (const float*)d_in[3];
  const float* Wo = (const float*)d_in[4];
  float* out = (float*)d_out;

  const size_t MB = 1024 * 1024;
  char* ws = (char*)d_ws;
  // workspace (96 MB). Ob aliases xb (dead after QKV GEMM).
  u16* xb  = (u16*)(ws);               // 16 MB [4096,2048] fp16 (later Ob)
  u16* Wqb = (u16*)(ws + 16 * MB);     //  8 MB each
  u16* Wkb = (u16*)(ws + 24 * MB);
  u16* Wvb = (u16*)(ws + 32 * MB);
  u16* Wob = (u16*)(ws + 40 * MB);
  u16* Qh  = (u16*)(ws + 48 * MB);     // 16 MB [BH,T,128]
  u16* Kh  = (u16*)(ws + 64 * MB);     // 16 MB
  u16* Vt  = (u16*)(ws + 80 * MB);     // 16 MB [BH,128,T]
  u16* Ob  = xb;

  const int nx = 2 * 2048 * 2048;
  const int nw = 2048 * 2048;

  f32_to_f16_kernel<<<nx / 1024, 256, 0, stream>>>(x, xb, nx);
  w4_to_f16_kernel<<<dim3(nw / 1024, 4), 256, 0, stream>>>(Wq, Wk, Wv, Wo, Wqb, Wkb, Wvb, Wob, nw);

  // fused QKV: N = 6144; V written pre-transposed
  gemm_bt<3><<<dim3(6144 / 128, 4096 / 128), 256, 0, stream>>>(
      xb, Wqb, Wkb, Wvb, (void*)Qh, (void*)Kh, (void*)Vt, 4096, 6144, 2048);

  attn_kernel<<<dim3(32, 16), 256, 0, stream>>>(Qh, Kh, Vt, Ob);

  gemm_bt<1><<<dim3(2048 / 128, 4096 / 128), 256, 0, stream>>>(
      Ob, Wob, nullptr, nullptr, (void*)out, nullptr, nullptr, 4096, 2048, 2048);
}

// Round 6
// 339.355 us; speedup vs baseline: 1.6564x; 1.6564x over previous
//
#include <hip/hip_runtime.h>
#include <stdint.h>

// GhostAttention on MI355X (gfx950). B=2, T=2048, C=2048, H=16, hd=128.
// All-fp16 pipeline: convert -> fused QKV GEMM (BK=64, conflict-free LDS;
// V written transposed via LDS epilogue) -> causal relu-attention
// (linear normalizer, k-tile=64, 3 barriers/iter, no Ps/Ks alias) ->
// out GEMM (fp32 out).
// NOTE (R5 post-mortem): k-tile=128 spilled (s[2][8]+oacc+qf > 128 VGPR ->
// 120 MB scratch traffic, attn 3x slower). Register budget is saturated at
// k-tile 64 — do not grow the S accumulator.

typedef unsigned short u16;
typedef _Float16 f16x8 __attribute__((ext_vector_type(8)));
typedef float floatx4 __attribute__((ext_vector_type(4)));
typedef unsigned short ushort8_t __attribute__((ext_vector_type(8)));

__device__ __forceinline__ u16 f2h(float f) {
  _Float16 h = (_Float16)f;                  // v_cvt_f16_f32, RNE
  return __builtin_bit_cast(u16, h);
}
__device__ __forceinline__ f16x8 ld_frag(const u16* p) {
  return __builtin_bit_cast(f16x8, *(const ushort8_t*)p);
}

// XOR-swizzled LDS offset: row length R elems (R%8==0), cprMask = R/8-1.
__device__ __forceinline__ int swz(int row, int col, int R, int cprMask) {
  int chunk = ((col >> 3) ^ row) & cprMask;
  return row * R + chunk * 8 + (col & 7);
}

__device__ __forceinline__ void async_copy16(const void* g, void* l) {
  __builtin_amdgcn_global_load_lds(
      (const __attribute__((address_space(1))) void*)g,
      (__attribute__((address_space(3))) void*)l, 16, 0, 0);
}

// Stage (NINST*2048/R) rows x R fp16 from global (row stride grs) into swizzled LDS.
template<int R, int NINST>
__device__ __forceinline__ void stage_swz(const u16* g, size_t grs, u16* lds, int tid) {
  constexpr int CPR = R / 8;
  #pragma unroll
  for (int i = 0; i < NINST; ++i) {
    int f = tid + i * 256;
    int row = f / CPR;
    int sc = f & (CPR - 1);
    int c = sc ^ (row & (CPR - 1));
    async_copy16(g + (size_t)row * grs + c * 8, (char*)lds + f * 16);
  }
}

// ---------------------------------------------------------------- converts
__global__ void f32_to_f16_kernel(const float* __restrict__ in, u16* __restrict__ out, int n) {
  int i = (blockIdx.x * blockDim.x + threadIdx.x) * 4;
  if (i < n) {
    float4 v = *(const float4*)(in + i);
    ushort4 o;
    o.x = f2h(v.x); o.y = f2h(v.y); o.z = f2h(v.z); o.w = f2h(v.w);
    *(ushort4*)(out + i) = o;
  }
}

__global__ void w4_to_f16_kernel(const float* w0, const float* w1, const float* w2, const float* w3,
                                 u16* o0, u16* o1, u16* o2, u16* o3, int n) {
  const float* in = (blockIdx.y == 0) ? w0 : (blockIdx.y == 1) ? w1 : (blockIdx.y == 2) ? w2 : w3;
  u16* out = (blockIdx.y == 0) ? o0 : (blockIdx.y == 1) ? o1 : (blockIdx.y == 2) ? o2 : o3;
  int i = (blockIdx.x * blockDim.x + threadIdx.x) * 4;
  if (i < n) {
    float4 v = *(const float4*)(in + i);
    ushort4 o;
    o.x = f2h(v.x); o.y = f2h(v.y); o.z = f2h(v.z); o.w = f2h(v.w);
    *(ushort4*)(out + i) = o;
  }
}

// ---------------------------------------------------------------- GEMM (B^T)
// C = A[M,K] @ B[N,K]^T, fp16 in, fp32 accum. 128x128 tile, BK=64.
// MODE 1: fp32 row-major C0[M,N]   (final projection)
// MODE 3: fused QKV: N=6144; sel = n/2048 -> Q (C0) / K (C1) head-major
//         [B,H,T,128]; V (C2) written TRANSPOSED [B,H,128,T] via LDS.
template<int MODE>
__global__ __launch_bounds__(256, 3) void gemm_bt(
    const u16* __restrict__ A,
    const u16* __restrict__ B0, const u16* __restrict__ B1, const u16* __restrict__ B2,
    void* __restrict__ C0, void* __restrict__ C1, void* __restrict__ C2,
    const int M, const int N, const int K)
{
  __shared__ __align__(16) u16 smem[128 * 128];  // 32 KB: As|Bs, reused by V-epilogue
  u16* As = smem;
  u16* Bs = smem + 128 * 64;
  const int tid = threadIdx.x;
  const int w = tid >> 6, lane = tid & 63, lr = lane & 15, lq = lane >> 4;
  const int bn0 = blockIdx.x * 128, bm0 = blockIdx.y * 128;
  const int wm = (w >> 1) * 64, wn = (w & 1) * 64;
  floatx4 acc[4][4] = {};
  const u16* Ab = A + (size_t)bm0 * K;
  const int sel = bn0 >> 11;                  // which output (MODE 3)
  const u16* Bb;
  if (MODE == 3) {
    const u16* Bsel = (sel == 0) ? B0 : (sel == 1) ? B1 : B2;
    Bb = Bsel + (size_t)(bn0 & 2047) * K;
  } else {
    Bb = B0 + (size_t)bn0 * K;
  }

  for (int k0 = 0; k0 < K; k0 += 64) {
    __syncthreads();
    stage_swz<64, 4>(Ab + k0, K, As, tid);
    stage_swz<64, 4>(Bb + k0, K, Bs, tid);
    __syncthreads();
    #pragma unroll
    for (int kk = 0; kk < 2; ++kk) {
      f16x8 af[4], bfr[4];
      #pragma unroll
      for (int t = 0; t < 4; ++t) {
        af[t]  = ld_frag(&As[swz(wm + t * 16 + lr, kk * 32 + lq * 8, 64, 7)]);
        bfr[t] = ld_frag(&Bs[swz(wn + t * 16 + lr, kk * 32 + lq * 8, 64, 7)]);
      }
      #pragma unroll
      for (int mt = 0; mt < 4; ++mt)
        #pragma unroll
        for (int nt = 0; nt < 4; ++nt)
          acc[mt][nt] = __builtin_amdgcn_mfma_f32_16x16x32_f16(af[mt], bfr[nt], acc[mt][nt], 0, 0, 0);
    }
  }

  // epilogue: C/D layout col=lane&15, row=(lane>>4)*4+reg
  if (MODE == 3 && sel == 2) {
    // V: transpose 128x128 tile through LDS, write Vt [BH,128,T] coalesced.
    __syncthreads();                          // all waves done reading As/Bs
    #pragma unroll
    for (int mt = 0; mt < 4; ++mt) {
      #pragma unroll
      for (int nt = 0; nt < 4; ++nt) {
        #pragma unroll
        for (int r = 0; r < 4; ++r) {
          const int tl = wm + mt * 16 + lq * 4 + r;   // local t
          const int d  = wn + nt * 16 + lr;           // local d
          smem[swz(d, tl, 128, 15)] = f2h(acc[mt][nt][r]);
        }
      }
    }
    __syncthreads();
    const int bb = bm0 >> 11, t0 = bm0 & 2047;
    const int h = (bn0 & 2047) >> 7;
    u16* base = (u16*)C2 + ((size_t)(bb * 16 + h) * 128) * 2048 + t0;
    #pragma unroll
    for (int i = 0; i < 8; ++i) {
      const int f = tid + i * 256;           // chunk id 0..2047
      const int row = f >> 4;                // local d
      const int cc = f & 15;                 // stored chunk
      const int c = cc ^ (row & 15);         // logical t-chunk
      ushort8_t v = *(const ushort8_t*)&smem[row * 128 + cc * 8];
      *(ushort8_t*)(base + (size_t)row * 2048 + c * 8) = v;
    }
  } else {
    #pragma unroll
    for (int mt = 0; mt < 4; ++mt) {
      #pragma unroll
      for (int nt = 0; nt < 4; ++nt) {
        #pragma unroll
        for (int r = 0; r < 4; ++r) {
          const int m = bm0 + wm + mt * 16 + lq * 4 + r;
          const int n = bn0 + wn + nt * 16 + lr;
          const float v = acc[mt][nt][r];
          if (MODE == 1) {
            ((float*)C0)[(size_t)m * N + n] = v;
          } else {
            const int nn = n & 2047;
            const int bb = m >> 11, t = m & 2047, h = nn >> 7, d = nn & 127;
            const size_t idx = (((size_t)(bb * 16 + h) * 2048) + t) * 128 + d;
            u16* Cs = (sel == 0) ? (u16*)C0 : (u16*)C1;
            Cs[idx] = f2h(v);
          }
        }
      }
    }
  }
}

// ---------------------------------------------------------------- attention
// Block: one (bh, 128-row q-tile). k-tiles of 64. out = (P@V)/(P@1 + eps),
// P = relu(S*scale + 0.1), causal. Ps in its OWN region (no Ks alias) ->
// 3 barriers/iter: [stage; B1; QK; P-write; B2; PV; B3]. LDS 48 KB, 2 blk/CU.
__global__ __launch_bounds__(256, 2) void attn_kernel(
    const u16* __restrict__ Qh, const u16* __restrict__ Kh,
    const u16* __restrict__ Vt, u16* __restrict__ Ob)
{
  __shared__ __align__(16) u16 smem[24576];   // 48 KB
  u16* Ks  = smem;            // [64 k][128 d]  swz cpr16
  u16* Vts = smem + 8192;     // [128 d][64 k]  swz cpr8
  u16* Ps  = smem + 16384;    // [128 q][64 k]  swz cpr8
  const int tid = threadIdx.x;
  const int w = tid >> 6, lane = tid & 63, lr = lane & 15, lq = lane >> 4;
  const int bh = blockIdx.x;
  const int y = blockIdx.y;
  // complementary interleave: blocks y and y+8 have qt summing to 15 ->
  // uniform k-iter load across CUs
  const int qt = (y < 8) ? (15 - y) : (y - 8);
  const int q0 = qt * 128;
  const size_t bhT = (size_t)bh * 2048;

  // Q tile 128x128 through smem (first 32 KB) -> registers
  f16x8 qf[2][4];
  stage_swz<128, 8>(Qh + (bhT + q0) * 128, 128, smem, tid);
  __syncthreads();
  #pragma unroll
  for (int mt = 0; mt < 2; ++mt)
    #pragma unroll
    for (int kk = 0; kk < 4; ++kk)
      qf[mt][kk] = ld_frag(&smem[swz(w * 32 + mt * 16 + lr, kk * 32 + lq * 8, 128, 15)]);
  __syncthreads();

  floatx4 oacc[2][8] = {};
  floatx4 den[2] = {};
  const ushort8_t onesu = {0x3C00, 0x3C00, 0x3C00, 0x3C00, 0x3C00, 0x3C00, 0x3C00, 0x3C00};
  const f16x8 ones = __builtin_bit_cast(f16x8, onesu);
  const float scale = 0.08838834764831845f;   // 1/sqrt(128)

  const int kend = q0 + 128;
  for (int k0 = 0; k0 < kend; k0 += 64) {
    stage_swz<128, 4>(Kh + (bhT + k0) * 128, 128, Ks, tid);
    stage_swz<64, 4>(Vt + (size_t)bh * 128 * 2048 + k0, 2048, Vts, tid);
    __syncthreads();                          // B1: staging visible

    // S = Q K^T : 32 q-rows x 64 keys per wave
    floatx4 s[2][4] = {};
    #pragma unroll
    for (int kk = 0; kk < 4; ++kk) {
      f16x8 kf[4];
      #pragma unroll
      for (int nt = 0; nt < 4; ++nt)
        kf[nt] = ld_frag(&Ks[swz(nt * 16 + lr, kk * 32 + lq * 8, 128, 15)]);
      #pragma unroll
      for (int mt = 0; mt < 2; ++mt)
        #pragma unroll
        for (int nt = 0; nt < 4; ++nt)
          s[mt][nt] = __builtin_amdgcn_mfma_f32_16x16x32_f16(qf[mt][kk], kf[nt], s[mt][nt], 0, 0, 0);
    }

    // P = relu(S*scale + 0.1) -> Ps (own region; prev-iter readers fenced by B3)
    if (k0 < q0) {                            // interior: no mask needed
      #pragma unroll
      for (int mt = 0; mt < 2; ++mt) {
        const int rb = w * 32 + mt * 16 + lq * 4;
        #pragma unroll
        for (int nt = 0; nt < 4; ++nt) {
          const int col = nt * 16 + lr;
          #pragma unroll
          for (int r = 0; r < 4; ++r)
            Ps[swz(rb + r, col, 64, 7)] = f2h(fmaxf(s[mt][nt][r] * scale + 0.1f, 0.0f));
        }
      }
    } else {
      #pragma unroll
      for (int mt = 0; mt < 2; ++mt) {
        const int rb = w * 32 + mt * 16 + lq * 4;
        #pragma unroll
        for (int nt = 0; nt < 4; ++nt) {
          const int col = nt * 16 + lr;
          const int kg = k0 + col;
          #pragma unroll
          for (int r = 0; r < 4; ++r) {
            float v = fmaxf(s[mt][nt][r] * scale + 0.1f, 0.0f);
            v = (kg <= q0 + rb + r) ? v : 0.0f;
            Ps[swz(rb + r, col, 64, 7)] = f2h(v);
          }
        }
      }
    }
    __syncthreads();                          // B2: Ps visible

    // O += P @ Vt^T ; den += P @ 1
    #pragma unroll
    for (int kk = 0; kk < 2; ++kk) {
      f16x8 pf[2];
      #pragma unroll
      for (int mt = 0; mt < 2; ++mt)
        pf[mt] = ld_frag(&Ps[swz(w * 32 + mt * 16 + lr, kk * 32 + lq * 8, 64, 7)]);
      #pragma unroll
      for (int mt = 0; mt < 2; ++mt)
        den[mt] = __builtin_amdgcn_mfma_f32_16x16x32_f16(pf[mt], ones, den[mt], 0, 0, 0);
      #pragma unroll
      for (int dt = 0; dt < 8; ++dt) {
        f16x8 vf = ld_frag(&Vts[swz(dt * 16 + lr, kk * 32 + lq * 8, 64, 7)]);
        #pragma unroll
        for (int mt = 0; mt < 2; ++mt)
          oacc[mt][dt] = __builtin_amdgcn_mfma_f32_16x16x32_f16(pf[mt], vf, oacc[mt][dt], 0, 0, 0);
      }
    }
    __syncthreads();                          // B3: done with Ks/Vts/Ps
  }

  // epilogue: Ob [B*T, 2048] fp16 (row = b*2048 + t, col = h*128 + d)
  const int b = bh >> 4, h = bh & 15;
  #pragma unroll
  for (int mt = 0; mt < 2; ++mt) {
    #pragma unroll
    for (int r = 0; r < 4; ++r) {
      const int qrow = w * 32 + mt * 16 + lq * 4 + r;
      const float inv = 1.0f / (den[mt][r] + 1e-6f);
      u16* dst = Ob + ((size_t)(b * 2048 + q0 + qrow)) * 2048 + h * 128;
      #pragma unroll
      for (int dt = 0; dt < 8; ++dt)
        dst[dt * 16 + lr] = f2h(oacc[mt][dt][r] * inv);
    }
  }
}

// ---------------------------------------------------------------- launch
extern "C" void kernel_launch(void* const* d_in, const int* in_sizes, int n_in,
                              void* d_out, int out_size, void* d_ws, size_t ws_size,
                              hipStream_t stream) {
  const float* x  = (const float*)d_in[0];
  const float* Wq = (const float*)d_in[1];
  const float* Wk = (const float*)d_in[2];
  const float* Wv = (const float*)d_in[3];
  const float* Wo = (const float*)d_in[4];
  float* out = (float*)d_out;

  const size_t MB = 1024 * 1024;
  char* ws = (char*)d_ws;
  // workspace (96 MB). Ob aliases xb (dead after QKV GEMM).
  u16* xb  = (u16*)(ws);               // 16 MB [4096,2048] fp16 (later Ob)
  u16* Wqb = (u16*)(ws + 16 * MB);     //  8 MB each
  u16* Wkb = (u16*)(ws + 24 * MB);
  u16* Wvb = (u16*)(ws + 32 * MB);
  u16* Wob = (u16*)(ws + 40 * MB);
  u16* Qh  = (u16*)(ws + 48 * MB);     // 16 MB [BH,T,128]
  u16* Kh  = (u16*)(ws + 64 * MB);     // 16 MB
  u16* Vt  = (u16*)(ws + 80 * MB);     // 16 MB [BH,128,T]
  u16* Ob  = xb;

  const int nx = 2 * 2048 * 2048;
  const int nw = 2048 * 2048;

  f32_to_f16_kernel<<<nx / 1024, 256, 0, stream>>>(x, xb, nx);
  w4_to_f16_kernel<<<dim3(nw / 1024, 4), 256, 0, stream>>>(Wq, Wk, Wv, Wo, Wqb, Wkb, Wvb, Wob, nw);

  // fused QKV: N = 6144; V written pre-transposed
  gemm_bt<3><<<dim3(6144 / 128, 4096 / 128), 256, 0, stream>>>(
      xb, Wqb, Wkb, Wvb, (void*)Qh, (void*)Kh, (void*)Vt, 4096, 6144, 2048);

  attn_kernel<<<dim3(32, 16), 256, 0, stream>>>(Qh, Kh, Vt, Ob);

  gemm_bt<1><<<dim3(2048 / 128, 4096 / 128), 256, 0, stream>>>(
      Ob, Wob, nullptr, nullptr, (void*)out, nullptr, nullptr, 4096, 2048, 2048);
}

// Round 7
// 334.984 us; speedup vs baseline: 1.6781x; 1.0130x over previous
//
#include <hip/hip_runtime.h>
#include <stdint.h>

// GhostAttention on MI355X (gfx950). B=2, T=2048, C=2048, H=16, hd=128.
// All-fp16 pipeline: convert (single launch) -> fused QKV GEMM (BK=64,
// conflict-free LDS; V written transposed via LDS epilogue) -> causal
// relu-attention (linear normalizer, k-tile=64, K/V double-buffered,
// 2 barriers/iter, QK wave-split 64q x 32k) -> out GEMM (fp32 out).
// NOTE (R5 post-mortem): attn register budget: s-tile growth beyond k=64
// spilled (~320 regs needed vs 256). Current peak ~200 regs - fits.

typedef unsigned short u16;
typedef _Float16 f16x8 __attribute__((ext_vector_type(8)));
typedef float floatx4 __attribute__((ext_vector_type(4)));
typedef unsigned short ushort8_t __attribute__((ext_vector_type(8)));

__device__ __forceinline__ u16 f2h(float f) {
  _Float16 h = (_Float16)f;                  // v_cvt_f16_f32, RNE
  return __builtin_bit_cast(u16, h);
}
__device__ __forceinline__ f16x8 ld_frag(const u16* p) {
  return __builtin_bit_cast(f16x8, *(const ushort8_t*)p);
}

// XOR-swizzled LDS offset: row length R elems (R%8==0), cprMask = R/8-1.
__device__ __forceinline__ int swz(int row, int col, int R, int cprMask) {
  int chunk = ((col >> 3) ^ row) & cprMask;
  return row * R + chunk * 8 + (col & 7);
}

__device__ __forceinline__ void async_copy16(const void* g, void* l) {
  __builtin_amdgcn_global_load_lds(
      (const __attribute__((address_space(1))) void*)g,
      (__attribute__((address_space(3))) void*)l, 16, 0, 0);
}

// Stage (NINST*2048/R) rows x R fp16 from global (row stride grs) into swizzled LDS.
template<int R, int NINST>
__device__ __forceinline__ void stage_swz(const u16* g, size_t grs, u16* lds, int tid) {
  constexpr int CPR = R / 8;
  #pragma unroll
  for (int i = 0; i < NINST; ++i) {
    int f = tid + i * 256;
    int row = f / CPR;
    int sc = f & (CPR - 1);
    int c = sc ^ (row & (CPR - 1));
    async_copy16(g + (size_t)row * grs + c * 8, (char*)lds + f * 16);
  }
}

// ---------------------------------------------------------------- converts
// One launch for all five fp32->fp16 conversions. Regions in float4 groups:
// x = 2^21 groups, each W = 2^20 groups.
__global__ void convert_all(const float* __restrict__ x,
                            const float* __restrict__ Wq, const float* __restrict__ Wk,
                            const float* __restrict__ Wv, const float* __restrict__ Wo,
                            u16* __restrict__ xb, u16* __restrict__ wqb, u16* __restrict__ wkb,
                            u16* __restrict__ wvb, u16* __restrict__ wob) {
  const int gi = blockIdx.x * 256 + threadIdx.x;   // float4-group index
  const float* src;
  u16* dst;
  int off;
  if (gi < (1 << 21)) {
    src = x; dst = xb; off = gi;
  } else {
    const int j = gi - (1 << 21);
    const int wsel = j >> 20;
    off = j & ((1 << 20) - 1);
    src = (wsel == 0) ? Wq : (wsel == 1) ? Wk : (wsel == 2) ? Wv : Wo;
    dst = (wsel == 0) ? wqb : (wsel == 1) ? wkb : (wsel == 2) ? wvb : wob;
  }
  float4 v = ((const float4*)src)[off];
  ushort4 o;
  o.x = f2h(v.x); o.y = f2h(v.y); o.z = f2h(v.z); o.w = f2h(v.w);
  ((ushort4*)dst)[off] = o;
}

// ---------------------------------------------------------------- GEMM (B^T)
// C = A[M,K] @ B[N,K]^T, fp16 in, fp32 accum. 128x128 tile, BK=64.
// MODE 1: fp32 row-major C0[M,N]   (final projection)
// MODE 3: fused QKV: N=6144; sel = n/2048 -> Q (C0) / K (C1) head-major
//         [B,H,T,128]; V (C2) written TRANSPOSED [B,H,128,T] via LDS.
template<int MODE>
__global__ __launch_bounds__(256, 3) void gemm_bt(
    const u16* __restrict__ A,
    const u16* __restrict__ B0, const u16* __restrict__ B1, const u16* __restrict__ B2,
    void* __restrict__ C0, void* __restrict__ C1, void* __restrict__ C2,
    const int M, const int N, const int K)
{
  __shared__ __align__(16) u16 smem[128 * 128];  // 32 KB: As|Bs, reused by V-epilogue
  u16* As = smem;
  u16* Bs = smem + 128 * 64;
  const int tid = threadIdx.x;
  const int w = tid >> 6, lane = tid & 63, lr = lane & 15, lq = lane >> 4;
  const int bn0 = blockIdx.x * 128, bm0 = blockIdx.y * 128;
  const int wm = (w >> 1) * 64, wn = (w & 1) * 64;
  floatx4 acc[4][4] = {};
  const u16* Ab = A + (size_t)bm0 * K;
  const int sel = bn0 >> 11;                  // which output (MODE 3)
  const u16* Bb;
  if (MODE == 3) {
    const u16* Bsel = (sel == 0) ? B0 : (sel == 1) ? B1 : B2;
    Bb = Bsel + (size_t)(bn0 & 2047) * K;
  } else {
    Bb = B0 + (size_t)bn0 * K;
  }

  for (int k0 = 0; k0 < K; k0 += 64) {
    __syncthreads();
    stage_swz<64, 4>(Ab + k0, K, As, tid);
    stage_swz<64, 4>(Bb + k0, K, Bs, tid);
    __syncthreads();
    #pragma unroll
    for (int kk = 0; kk < 2; ++kk) {
      f16x8 af[4], bfr[4];
      #pragma unroll
      for (int t = 0; t < 4; ++t) {
        af[t]  = ld_frag(&As[swz(wm + t * 16 + lr, kk * 32 + lq * 8, 64, 7)]);
        bfr[t] = ld_frag(&Bs[swz(wn + t * 16 + lr, kk * 32 + lq * 8, 64, 7)]);
      }
      #pragma unroll
      for (int mt = 0; mt < 4; ++mt)
        #pragma unroll
        for (int nt = 0; nt < 4; ++nt)
          acc[mt][nt] = __builtin_amdgcn_mfma_f32_16x16x32_f16(af[mt], bfr[nt], acc[mt][nt], 0, 0, 0);
    }
  }

  // epilogue: C/D layout col=lane&15, row=(lane>>4)*4+reg
  if (MODE == 3 && sel == 2) {
    // V: transpose 128x128 tile through LDS, write Vt [BH,128,T] coalesced.
    __syncthreads();                          // all waves done reading As/Bs
    #pragma unroll
    for (int mt = 0; mt < 4; ++mt) {
      #pragma unroll
      for (int nt = 0; nt < 4; ++nt) {
        #pragma unroll
        for (int r = 0; r < 4; ++r) {
          const int tl = wm + mt * 16 + lq * 4 + r;   // local t
          const int d  = wn + nt * 16 + lr;           // local d
          smem[swz(d, tl, 128, 15)] = f2h(acc[mt][nt][r]);
        }
      }
    }
    __syncthreads();
    const int bb = bm0 >> 11, t0 = bm0 & 2047;
    const int h = (bn0 & 2047) >> 7;
    u16* base = (u16*)C2 + ((size_t)(bb * 16 + h) * 128) * 2048 + t0;
    #pragma unroll
    for (int i = 0; i < 8; ++i) {
      const int f = tid + i * 256;           // chunk id 0..2047
      const int row = f >> 4;                // local d
      const int cc = f & 15;                 // stored chunk
      const int c = cc ^ (row & 15);         // logical t-chunk
      ushort8_t v = *(const ushort8_t*)&smem[row * 128 + cc * 8];
      *(ushort8_t*)(base + (size_t)row * 2048 + c * 8) = v;
    }
  } else {
    #pragma unroll
    for (int mt = 0; mt < 4; ++mt) {
      #pragma unroll
      for (int nt = 0; nt < 4; ++nt) {
        #pragma unroll
        for (int r = 0; r < 4; ++r) {
          const int m = bm0 + wm + mt * 16 + lq * 4 + r;
          const int n = bn0 + wn + nt * 16 + lr;
          const float v = acc[mt][nt][r];
          if (MODE == 1) {
            ((float*)C0)[(size_t)m * N + n] = v;
          } else {
            const int nn = n & 2047;
            const int bb = m >> 11, t = m & 2047, h = nn >> 7, d = nn & 127;
            const size_t idx = (((size_t)(bb * 16 + h) * 2048) + t) * 128 + d;
            u16* Cs = (sel == 0) ? (u16*)C0 : (u16*)C1;
            Cs[idx] = f2h(v);
          }
        }
      }
    }
  }
}

// ---------------------------------------------------------------- attention
// Block: one (bh, 128-row q-tile). k-tiles of 64, K/V double-buffered:
// per iter [B1: staging visible + prev PV fenced; issue prefetch; QK; P-write;
// B2: Ps visible (drains prefetch after QK overlap); PV]. 2 barriers/iter.
// QK wave-split 64q x 32k: each kf LDS read feeds 4 MFMAs (was 2).
// LDS 80 KB: Ks0|Ks1|Vts0|Vts1|Ps -> 2 blocks/CU.
__global__ __launch_bounds__(256, 2) void attn_kernel(
    const u16* __restrict__ Qh, const u16* __restrict__ Kh,
    const u16* __restrict__ Vt, u16* __restrict__ Ob)
{
  __shared__ __align__(16) u16 smem[40960];   // 80 KB
  const int tid = threadIdx.x;
  const int w = tid >> 6, lane = tid & 63, lr = lane & 15, lq = lane >> 4;
  const int bh = blockIdx.x;
  const int y = blockIdx.y;
  // complementary interleave: blocks y and y+8 have qt summing to 15 ->
  // uniform k-iter load across CUs
  const int qt = (y < 8) ? (15 - y) : (y - 8);
  const int q0 = qt * 128;
  const size_t bhT = (size_t)bh * 2048;
  const u16* Vtb = Vt + (size_t)bh * 128 * 2048;

  // Q tile 128x128 staged through smem[0..16383] -> registers (64 q-rows/wave)
  stage_swz<128, 8>(Qh + (bhT + q0) * 128, 128, smem, tid);
  __syncthreads();
  const int mq0 = (w >> 1) * 64, nk0 = (w & 1) * 32;
  f16x8 qf[4][4];
  #pragma unroll
  for (int mt = 0; mt < 4; ++mt)
    #pragma unroll
    for (int kk = 0; kk < 4; ++kk)
      qf[mt][kk] = ld_frag(&smem[swz(mq0 + mt * 16 + lr, kk * 32 + lq * 8, 128, 15)]);
  __syncthreads();                            // Q reads done before K staging

  // prefetch first K/V tile into buffer 0
  stage_swz<128, 4>(Kh + (bhT + 0) * 128, 128, smem, tid);
  stage_swz<64, 4>(Vtb + 0, 2048, smem + 16384, tid);

  floatx4 oacc[2][8] = {};
  floatx4 den[2] = {};
  const ushort8_t onesu = {0x3C00, 0x3C00, 0x3C00, 0x3C00, 0x3C00, 0x3C00, 0x3C00, 0x3C00};
  const f16x8 ones = __builtin_bit_cast(f16x8, onesu);
  const float scale = 0.08838834764831845f;   // 1/sqrt(128)

  const int kend = q0 + 128;
  int buf = 0;
  for (int k0 = 0; k0 < kend; k0 += 64) {
    u16* Ks  = smem + buf * 8192;             // [64 k][128 d] swz cpr16
    u16* Vts = smem + 16384 + buf * 8192;     // [128 d][64 k] swz cpr8
    u16* Ps  = smem + 32768;                  // [128 q][64 k] swz cpr8
    __syncthreads();                          // B1: cur staging visible; prev PV fenced

    if (k0 + 64 < kend) {                     // issue prefetch of next tile (async)
      stage_swz<128, 4>(Kh + (bhT + k0 + 64) * 128, 128, smem + (buf ^ 1) * 8192, tid);
      stage_swz<64, 4>(Vtb + k0 + 64, 2048, smem + 16384 + (buf ^ 1) * 8192, tid);
    }

    // S = Q K^T : 64 q-rows x 32 keys per wave (kf read feeds 4 MFMAs)
    floatx4 s[4][2] = {};
    #pragma unroll
    for (int kk = 0; kk < 4; ++kk) {
      f16x8 kf[2];
      #pragma unroll
      for (int nt = 0; nt < 2; ++nt)
        kf[nt] = ld_frag(&Ks[swz(nk0 + nt * 16 + lr, kk * 32 + lq * 8, 128, 15)]);
      #pragma unroll
      for (int mt = 0; mt < 4; ++mt)
        #pragma unroll
        for (int nt = 0; nt < 2; ++nt)
          s[mt][nt] = __builtin_amdgcn_mfma_f32_16x16x32_f16(qf[mt][kk], kf[nt], s[mt][nt], 0, 0, 0);
    }

    // P = relu(S*scale + 0.1) -> Ps; causal mask only on diagonal-band tiles
    if (k0 < q0) {                            // interior: no mask needed
      #pragma unroll
      for (int mt = 0; mt < 4; ++mt) {
        const int rb = mq0 + mt * 16 + lq * 4;
        #pragma unroll
        for (int nt = 0; nt < 2; ++nt) {
          const int col = nk0 + nt * 16 + lr;
          #pragma unroll
          for (int r = 0; r < 4; ++r)
            Ps[swz(rb + r, col, 64, 7)] = f2h(fmaxf(s[mt][nt][r] * scale + 0.1f, 0.0f));
        }
      }
    } else {
      #pragma unroll
      for (int mt = 0; mt < 4; ++mt) {
        const int rb = mq0 + mt * 16 + lq * 4;
        #pragma unroll
        for (int nt = 0; nt < 2; ++nt) {
          const int col = nk0 + nt * 16 + lr;
          const int kg = k0 + col;
          #pragma unroll
          for (int r = 0; r < 4; ++r) {
            float v = fmaxf(s[mt][nt][r] * scale + 0.1f, 0.0f);
            v = (kg <= q0 + rb + r) ? v : 0.0f;
            Ps[swz(rb + r, col, 64, 7)] = f2h(v);
          }
        }
      }
    }
    __syncthreads();                          // B2: Ps visible

    // O += P @ Vt^T ; den += P @ 1   (wave w: q rows w*32..w*32+31, all d)
    #pragma unroll
    for (int kk = 0; kk < 2; ++kk) {
      f16x8 pf[2];
      #pragma unroll
      for (int mt = 0; mt < 2; ++mt)
        pf[mt] = ld_frag(&Ps[swz(w * 32 + mt * 16 + lr, kk * 32 + lq * 8, 64, 7)]);
      #pragma unroll
      for (int mt = 0; mt < 2; ++mt)
        den[mt] = __builtin_amdgcn_mfma_f32_16x16x32_f16(pf[mt], ones, den[mt], 0, 0, 0);
      #pragma unroll
      for (int dt = 0; dt < 8; ++dt) {
        f16x8 vf = ld_frag(&Vts[swz(dt * 16 + lr, kk * 32 + lq * 8, 64, 7)]);
        #pragma unroll
        for (int mt = 0; mt < 2; ++mt)
          oacc[mt][dt] = __builtin_amdgcn_mfma_f32_16x16x32_f16(pf[mt], vf, oacc[mt][dt], 0, 0, 0);
      }
    }
    buf ^= 1;
  }

  // epilogue: Ob [B*T, 2048] fp16 (row = b*2048 + t, col = h*128 + d)
  const int b = bh >> 4, h = bh & 15;
  #pragma unroll
  for (int mt = 0; mt < 2; ++mt) {
    #pragma unroll
    for (int r = 0; r < 4; ++r) {
      const int qrow = w * 32 + mt * 16 + lq * 4 + r;
      const float inv = 1.0f / (den[mt][r] + 1e-6f);
      u16* dst = Ob + ((size_t)(b * 2048 + q0 + qrow)) * 2048 + h * 128;
      #pragma unroll
      for (int dt = 0; dt < 8; ++dt)
        dst[dt * 16 + lr] = f2h(oacc[mt][dt][r] * inv);
    }
  }
}

// ---------------------------------------------------------------- launch
extern "C" void kernel_launch(void* const* d_in, const int* in_sizes, int n_in,
                              void* d_out, int out_size, void* d_ws, size_t ws_size,
                              hipStream_t stream) {
  const float* x  = (const float*)d_in[0];
  const float* Wq = (const float*)d_in[1];
  const float* Wk = (const float*)d_in[2];
  const float* Wv = (const float*)d_in[3];
  const float* Wo = (const float*)d_in[4];
  float* out = (float*)d_out;

  const size_t MB = 1024 * 1024;
  char* ws = (char*)d_ws;
  // workspace (96 MB). Ob aliases xb (dead after QKV GEMM).
  u16* xb  = (u16*)(ws);               // 16 MB [4096,2048] fp16 (later Ob)
  u16* Wqb = (u16*)(ws + 16 * MB);     //  8 MB each
  u16* Wkb = (u16*)(ws + 24 * MB);
  u16* Wvb = (u16*)(ws + 32 * MB);
  u16* Wob = (u16*)(ws + 40 * MB);
  u16* Qh  = (u16*)(ws + 48 * MB);     // 16 MB [BH,T,128]
  u16* Kh  = (u16*)(ws + 64 * MB);     // 16 MB
  u16* Vt  = (u16*)(ws + 80 * MB);     // 16 MB [BH,128,T]
  u16* Ob  = xb;

  // all converts in one launch: (2^21 + 4*2^20) float4 groups / 256 threads
  convert_all<<<24576, 256, 0, stream>>>(x, Wq, Wk, Wv, Wo, xb, Wqb, Wkb, Wvb, Wob);

  // fused QKV: N = 6144; V written pre-transposed
  gemm_bt<3><<<dim3(6144 / 128, 4096 / 128), 256, 0, stream>>>(
      xb, Wqb, Wkb, Wvb, (void*)Qh, (void*)Kh, (void*)Vt, 4096, 6144, 2048);

  attn_kernel<<<dim3(32, 16), 256, 0, stream>>>(Qh, Kh, Vt, Ob);

  gemm_bt<1><<<dim3(2048 / 128, 4096 / 128), 256, 0, stream>>>(
      Ob, Wob, nullptr, nullptr, (void*)out, nullptr, nullptr, 4096, 2048, 2048);
}